// Round 1
// baseline (38.737 us; speedup 1.0000x reference)
//
#include <hip/hip_runtime.h>

#define ROWS   1024
#define COLS   32768
#define BLOCK  256
#define NWAVE  (BLOCK / 64)      // 4 waves per block
#define VEC    8                 // elements per thread per tile
#define TILE   (BLOCK * VEC)     // 2048 elements per tile
#define NTILES (COLS / TILE)     // 16 tiles per row

__global__ __launch_bounds__(BLOCK) void cumprod_rows_kernel(
    const float* __restrict__ x, float* __restrict__ out) {
    __shared__ float s_wave[NWAVE];

    const int row  = blockIdx.x;
    const int tid  = threadIdx.x;
    const int lane = tid & 63;
    const int wave = tid >> 6;

    const float* __restrict__ xrow = x   + (size_t)row * COLS;
    float* __restrict__       orow = out + (size_t)row * COLS;

    float carry = 1.0f;   // product of all preceding tiles (uniform across block)

    for (int t = 0; t < NTILES; ++t) {
        const int base = t * TILE + tid * VEC;

        // Coalesced 32 B/lane vector loads.
        float4 a = *reinterpret_cast<const float4*>(xrow + base);
        float4 b = *reinterpret_cast<const float4*>(xrow + base + 4);

        // Local inclusive product chain over 8 elements.
        float p0 = a.x;
        float p1 = p0 * a.y;
        float p2 = p1 * a.z;
        float p3 = p2 * a.w;
        float p4 = p3 * b.x;
        float p5 = p4 * b.y;
        float p6 = p5 * b.z;
        float p7 = p6 * b.w;

        // Wave-level inclusive scan (product) of per-thread totals.
        float incl = p7;
        #pragma unroll
        for (int d = 1; d < 64; d <<= 1) {
            float other = __shfl_up(incl, d, 64);
            if (lane >= d) incl *= other;
        }
        // Exclusive version for this thread.
        float excl = __shfl_up(incl, 1, 64);
        if (lane == 0) excl = 1.0f;

        // Cross-wave combine: wave totals through LDS.
        if (lane == 63) s_wave[wave] = incl;
        __syncthreads();

        float wpre = 1.0f;   // product of earlier waves' totals (this tile)
        float btot = 1.0f;   // whole-tile product
        #pragma unroll
        for (int w = 0; w < NWAVE; ++w) {
            float v = s_wave[w];
            if (w < wave) wpre *= v;
            btot *= v;
        }
        __syncthreads();     // reads done before next tile rewrites s_wave

        const float pref = carry * wpre * excl;

        float4 o0, o1;
        o0.x = pref * p0; o0.y = pref * p1; o0.z = pref * p2; o0.w = pref * p3;
        o1.x = pref * p4; o1.y = pref * p5; o1.z = pref * p6; o1.w = pref * p7;
        *reinterpret_cast<float4*>(orow + base)     = o0;
        *reinterpret_cast<float4*>(orow + base + 4) = o1;

        carry *= btot;
    }
}

extern "C" void kernel_launch(void* const* d_in, const int* in_sizes, int n_in,
                              void* d_out, int out_size, void* d_ws, size_t ws_size,
                              hipStream_t stream) {
    const float* x = (const float*)d_in[0];
    float* out     = (float*)d_out;
    cumprod_rows_kernel<<<dim3(ROWS), dim3(BLOCK), 0, stream>>>(x, out);
}